// Round 1
// baseline (299.472 us; speedup 1.0000x reference)
//
#include <hip/hip_runtime.h>
#include <math.h>

// Problem constants (from reference setup_inputs)
#define B_  2
#define T_  2048
#define D_  512
#define H_  8
#define HD_ 64        // head dim
#define WHALF_ 16     // LOCAL_WINDOW/2
#define WIN_ 32

// ---------------------------------------------------------------------------
// Tiled fp32 GEMM:  C[M,N] = A[M,K] @ W[N,K]^T + bias[N]
// TM=TN=64, TK=16, 256 threads, 4x4 micro-tile per thread.
// ---------------------------------------------------------------------------
#define TM 64
#define TN 64
#define TK 16
#define LDP 68   // padded leading dim (68*4B = 272B, 16B-aligned rows, 2-way banks only)

__global__ __launch_bounds__(256) void gemm_bias_nt(
    const float* __restrict__ A,     // M x K row-major
    const float* __restrict__ W,     // N x K row-major
    const float* __restrict__ bias,  // N
    float* __restrict__ C,           // M x N row-major
    int M, int N, int K)
{
    __shared__ float As[TK][LDP];
    __shared__ float Bs[TK][LDP];

    const int tid = threadIdx.x;
    const int m0 = blockIdx.x * TM;
    const int n0 = blockIdx.y * TN;

    const int tx = tid & 15;   // n micro index
    const int ty = tid >> 4;   // m micro index

    // loader mapping: 256 threads, each loads one float4 of the 64x16 tile
    const int lr = tid >> 2;        // row 0..63
    const int lc = (tid & 3) * 4;   // k offset 0,4,8,12

    float acc[4][4] = {};

    for (int k0 = 0; k0 < K; k0 += TK) {
        float4 a4 = *(const float4*)(&A[(size_t)(m0 + lr) * K + k0 + lc]);
        float4 b4 = *(const float4*)(&W[(size_t)(n0 + lr) * K + k0 + lc]);
        As[lc + 0][lr] = a4.x; As[lc + 1][lr] = a4.y;
        As[lc + 2][lr] = a4.z; As[lc + 3][lr] = a4.w;
        Bs[lc + 0][lr] = b4.x; Bs[lc + 1][lr] = b4.y;
        Bs[lc + 2][lr] = b4.z; Bs[lc + 3][lr] = b4.w;
        __syncthreads();

        #pragma unroll
        for (int kk = 0; kk < TK; ++kk) {
            float4 ra4 = *(const float4*)(&As[kk][ty * 4]);
            float4 rb4 = *(const float4*)(&Bs[kk][tx * 4]);
            float ra[4] = {ra4.x, ra4.y, ra4.z, ra4.w};
            float rb[4] = {rb4.x, rb4.y, rb4.z, rb4.w};
            #pragma unroll
            for (int i = 0; i < 4; ++i)
                #pragma unroll
                for (int j = 0; j < 4; ++j)
                    acc[i][j] = fmaf(ra[i], rb[j], acc[i][j]);
        }
        __syncthreads();
    }

    // epilogue: bias + vectorized store
    float4 bb = *(const float4*)(&bias[n0 + tx * 4]);
    float bv[4] = {bb.x, bb.y, bb.z, bb.w};
    #pragma unroll
    for (int i = 0; i < 4; ++i) {
        int m = m0 + ty * 4 + i;
        float4 o;
        o.x = acc[i][0] + bv[0];
        o.y = acc[i][1] + bv[1];
        o.z = acc[i][2] + bv[2];
        o.w = acc[i][3] + bv[3];
        *(float4*)(&C[(size_t)m * N + n0 + tx * 4]) = o;
    }
}

// ---------------------------------------------------------------------------
// Local-window attention. One wave (64 threads) per (b,h,i) query row.
// q,k,v laid out (B*T, D) with head h occupying columns [h*64, h*64+64).
// ---------------------------------------------------------------------------
__global__ __launch_bounds__(64) void attn_local(
    const float* __restrict__ q, const float* __restrict__ k,
    const float* __restrict__ v, float* __restrict__ att)
{
    const int r  = blockIdx.x;          // b*H*T + h*T + i
    const int i  = r % T_;
    const int bh = r / T_;
    const int h  = bh % H_;
    const int b  = bh / H_;
    const int d  = threadIdx.x;         // 0..63

    const int jstart = (i - WHALF_ > 0) ? (i - WHALF_) : 0;
    const int jend   = (i + WHALF_ < T_) ? (i + WHALF_) : T_;
    const int cnt    = jend - jstart;

    const size_t rowQ = (size_t)(b * T_ + i) * D_ + h * HD_;
    const float qd = q[rowQ + d];

    __shared__ float s[WIN_];
    __shared__ float p[WIN_];

    // scores
    for (int jj = 0; jj < WIN_; ++jj) {
        float prod = 0.f;
        if (jj < cnt) {
            const size_t rowK = (size_t)(b * T_ + jstart + jj) * D_ + h * HD_;
            prod = qd * k[rowK + d];
        }
        #pragma unroll
        for (int m = 32; m > 0; m >>= 1)
            prod += __shfl_xor(prod, m, 64);
        if (d == 0) s[jj] = (jj < cnt) ? prod * 0.125f : -1e30f;
    }
    __syncthreads();

    // softmax (redundant per-lane broadcast reads — cheap)
    float mx = -1e30f;
    #pragma unroll
    for (int jj = 0; jj < WIN_; ++jj) mx = fmaxf(mx, s[jj]);
    if (d < WIN_) p[d] = __expf(s[d] - mx);
    __syncthreads();
    float denom = 0.f;
    #pragma unroll
    for (int jj = 0; jj < WIN_; ++jj) denom += p[jj];

    // weighted sum of v rows
    float acc = 0.f;
    for (int jj = 0; jj < cnt; ++jj) {
        const size_t rowV = (size_t)(b * T_ + jstart + jj) * D_ + h * HD_;
        acc = fmaf(p[jj], v[rowV + d], acc);
    }
    att[rowQ + d] = acc / denom;
}

// ---------------------------------------------------------------------------
extern "C" void kernel_launch(void* const* d_in, const int* in_sizes, int n_in,
                              void* d_out, int out_size, void* d_ws, size_t ws_size,
                              hipStream_t stream) {
    const float* x  = (const float*)d_in[0];
    const float* Wq = (const float*)d_in[1];
    const float* bq = (const float*)d_in[2];
    const float* Wk = (const float*)d_in[3];
    const float* bk = (const float*)d_in[4];
    const float* Wv = (const float*)d_in[5];
    const float* bv = (const float*)d_in[6];
    const float* Wo = (const float*)d_in[7];
    const float* bo = (const float*)d_in[8];
    float* out = (float*)d_out;

    const int M = B_ * T_;   // 4096
    float* q   = (float*)d_ws;
    float* k   = q + (size_t)M * D_;
    float* v   = k + (size_t)M * D_;
    float* att = v + (size_t)M * D_;

    dim3 gg(M / TM, D_ / TN);   // 64 x 8
    gemm_bias_nt<<<gg, 256, 0, stream>>>(x, Wq, bq, q, M, D_, D_);
    gemm_bias_nt<<<gg, 256, 0, stream>>>(x, Wk, bk, k, M, D_, D_);
    gemm_bias_nt<<<gg, 256, 0, stream>>>(x, Wv, bv, v, M, D_, D_);

    attn_local<<<B_ * H_ * T_, 64, 0, stream>>>(q, k, v, att);

    gemm_bias_nt<<<gg, 256, 0, stream>>>(att, Wo, bo, out, M, D_, D_);
}

// Round 2
// 150.061 us; speedup vs baseline: 1.9957x; 1.9957x over previous
//
#include <hip/hip_runtime.h>

#define B_  2
#define T_  2048
#define D_  512
#define H_  8
#define HD_ 64
#define WHALF_ 16
#define WIN_ 32
#define Mtot (B_*T_)

typedef __attribute__((ext_vector_type(8))) short short8;   // 8 bf16 in 4 VGPRs
typedef __attribute__((ext_vector_type(4))) float floatx4;  // MFMA accumulator

__device__ __forceinline__ unsigned short f2bf(float f) {
    unsigned u = __float_as_uint(f);
    u = (u + 0x7fffu + ((u >> 16) & 1u)) >> 16;   // round-to-nearest-even
    return (unsigned short)u;
}

// ---------------------------------------------------------------------------
// fp32 -> bf16 cast, 4 elements/thread
// ---------------------------------------------------------------------------
__global__ void cast_f32_bf16(const float* __restrict__ src,
                              unsigned short* __restrict__ dst, int n4) {
    int i = blockIdx.x * blockDim.x + threadIdx.x;
    if (i < n4) {
        float4 f = ((const float4*)src)[i];
        ushort4 o;
        o.x = f2bf(f.x); o.y = f2bf(f.y); o.z = f2bf(f.z); o.w = f2bf(f.w);
        ((ushort4*)dst)[i] = o;
    }
}

// ---------------------------------------------------------------------------
// bf16 MFMA GEMM:  C[M,N] = A[M,K](bf16) @ W[N,K](bf16)^T + bias, fp32 out.
// Tile 128(M) x 64(N), BK=32. 256 threads = 4 waves; wave w: wm=w&1 (64-row
// half), wn=w>>1 (32-col half); 4x2 grid of 16x16 frags per wave.
// LDS rows padded to 40 bf16 (80 B): 16B-aligned rows, 2-way banks (free).
// ---------------------------------------------------------------------------
#define GTM 128
#define GTN 64
#define GBK 32
#define ALD 40

__global__ __launch_bounds__(256) void gemm_bf16_nt(
    const unsigned short* __restrict__ A, const unsigned short* __restrict__ W,
    const float* __restrict__ bias, float* __restrict__ C,
    int M, int N, int K)
{
    __shared__ unsigned short As[GTM][ALD];
    __shared__ unsigned short Bs[GTN][ALD];

    const int t  = threadIdx.x;
    const int m0 = blockIdx.x * GTM;
    const int n0 = blockIdx.y * GTN;
    const int w  = t >> 6, l = t & 63;
    const int quad = l >> 4, lo = l & 15;
    const int wm = w & 1, wn = w >> 1;

    // loader mapping: chunk c -> row c>>2, k-offset (c&3)*8
    const int lrowA0 = t >> 2;           // chunks t       (rows 0..63)
    const int lrowA1 = (t + 256) >> 2;   // chunks t+256   (rows 64..127)
    const int lko    = (t & 3) * 8;

    floatx4 acc[4][2];
    #pragma unroll
    for (int i = 0; i < 4; ++i)
        #pragma unroll
        for (int j = 0; j < 2; ++j)
            acc[i][j] = (floatx4)0.0f;

    for (int k0 = 0; k0 < K; k0 += GBK) {
        *(short8*)(&As[lrowA0][lko]) =
            *(const short8*)(&A[(size_t)(m0 + lrowA0) * K + k0 + lko]);
        *(short8*)(&As[lrowA1][lko]) =
            *(const short8*)(&A[(size_t)(m0 + lrowA1) * K + k0 + lko]);
        *(short8*)(&Bs[lrowA0][lko]) =
            *(const short8*)(&W[(size_t)(n0 + lrowA0) * K + k0 + lko]);
        __syncthreads();

        short8 b0 = *(const short8*)(&Bs[wn * 32 + lo][quad * 8]);
        short8 b1 = *(const short8*)(&Bs[wn * 32 + 16 + lo][quad * 8]);
        #pragma unroll
        for (int i = 0; i < 4; ++i) {
            short8 a = *(const short8*)(&As[wm * 64 + i * 16 + lo][quad * 8]);
            acc[i][0] = __builtin_amdgcn_mfma_f32_16x16x32_bf16(a, b0, acc[i][0], 0, 0, 0);
            acc[i][1] = __builtin_amdgcn_mfma_f32_16x16x32_bf16(a, b1, acc[i][1], 0, 0, 0);
        }
        __syncthreads();
    }

    // epilogue: C/D layout col=lane&15, row=quad*4+reg
    #pragma unroll
    for (int i = 0; i < 4; ++i) {
        int rbase = m0 + wm * 64 + i * 16 + quad * 4;
        #pragma unroll
        for (int jn = 0; jn < 2; ++jn) {
            int col = n0 + wn * 32 + jn * 16 + lo;
            float bv = bias[col];
            #pragma unroll
            for (int r = 0; r < 4; ++r)
                C[(size_t)(rbase + r) * N + col] = acc[i][jn][r] + bv;
        }
    }
}

// ---------------------------------------------------------------------------
// Local-window attention, fp32 in / bf16 out (fused cast for O-projection).
// Block = 256 threads handles 64 query rows of one (b,h).
// K/V rows [q0-16, q0+80) staged in LDS (96 x 64, stride 65 -> conflict-free).
// Thread (row=t>>2, part=t&3): 16-dim slice; scores combined via 2 shfl_xor.
// ---------------------------------------------------------------------------
#define QTB 64
#define KROWS 96
#define VLD 65

__global__ __launch_bounds__(256) void attn_local(
    const float* __restrict__ q, const float* __restrict__ k,
    const float* __restrict__ v, unsigned short* __restrict__ att)
{
    __shared__ float Ks[KROWS][VLD];
    __shared__ float Vs[KROWS][VLD];

    const int q0 = blockIdx.x * QTB;
    const int bh = blockIdx.y;
    const int b  = bh >> 3, h = bh & 7;
    const int t  = threadIdx.x;

    // stage K/V window
    for (int c = t; c < KROWS * 16; c += 256) {
        int row  = c >> 4;
        int col4 = (c & 15) * 4;
        int glob = q0 - WHALF_ + row;
        float4 kv = make_float4(0.f, 0.f, 0.f, 0.f);
        float4 vv = make_float4(0.f, 0.f, 0.f, 0.f);
        if (glob >= 0 && glob < T_) {
            size_t base = ((size_t)(b * T_ + glob)) * D_ + h * HD_ + col4;
            kv = *(const float4*)(&k[base]);
            vv = *(const float4*)(&v[base]);
        }
        Ks[row][col4 + 0] = kv.x; Ks[row][col4 + 1] = kv.y;
        Ks[row][col4 + 2] = kv.z; Ks[row][col4 + 3] = kv.w;
        Vs[row][col4 + 0] = vv.x; Vs[row][col4 + 1] = vv.y;
        Vs[row][col4 + 2] = vv.z; Vs[row][col4 + 3] = vv.w;
    }
    __syncthreads();

    const int row  = t >> 2;       // 0..63 query row within block
    const int part = t & 3;        // 16-dim slice
    const int i    = q0 + row;
    const size_t qbase = ((size_t)(b * T_ + i)) * D_ + h * HD_ + part * 16;

    float qr[16];
    #pragma unroll
    for (int c = 0; c < 4; ++c) {
        float4 f = *(const float4*)(&q[qbase + c * 4]);
        qr[c * 4 + 0] = f.x; qr[c * 4 + 1] = f.y;
        qr[c * 4 + 2] = f.z; qr[c * 4 + 3] = f.w;
    }

    float s[WIN_];
    #pragma unroll
    for (int jj = 0; jj < WIN_; ++jj) {
        int slot = row + jj;       // LDS row = (i-16+jj) - (q0-16)
        float dot = 0.f;
        #pragma unroll
        for (int ii = 0; ii < 16; ++ii)
            dot = fmaf(qr[ii], Ks[slot][part * 16 + ii], dot);
        dot += __shfl_xor(dot, 1, 64);
        dot += __shfl_xor(dot, 2, 64);
        int glob = i - WHALF_ + jj;
        s[jj] = (glob >= 0 && glob < T_) ? dot * 0.125f : -1e30f;
    }

    float mx = -1e30f;
    #pragma unroll
    for (int jj = 0; jj < WIN_; ++jj) mx = fmaxf(mx, s[jj]);
    float den = 0.f;
    #pragma unroll
    for (int jj = 0; jj < WIN_; ++jj) { s[jj] = __expf(s[jj] - mx); den += s[jj]; }
    float inv = 1.0f / den;

    float o[16];
    #pragma unroll
    for (int ii = 0; ii < 16; ++ii) o[ii] = 0.f;
    #pragma unroll
    for (int jj = 0; jj < WIN_; ++jj) {
        int slot = row + jj;
        float p = s[jj];
        #pragma unroll
        for (int ii = 0; ii < 16; ++ii)
            o[ii] = fmaf(p, Vs[slot][part * 16 + ii], o[ii]);
    }

    #pragma unroll
    for (int c = 0; c < 4; ++c) {
        ushort4 ob;
        ob.x = f2bf(o[c * 4 + 0] * inv);
        ob.y = f2bf(o[c * 4 + 1] * inv);
        ob.z = f2bf(o[c * 4 + 2] * inv);
        ob.w = f2bf(o[c * 4 + 3] * inv);
        *(ushort4*)(&att[qbase + c * 4]) = ob;
    }
}

// ---------------------------------------------------------------------------
extern "C" void kernel_launch(void* const* d_in, const int* in_sizes, int n_in,
                              void* d_out, int out_size, void* d_ws, size_t ws_size,
                              hipStream_t stream) {
    const float* x  = (const float*)d_in[0];
    const float* Wq = (const float*)d_in[1];
    const float* bq = (const float*)d_in[2];
    const float* Wk = (const float*)d_in[3];
    const float* bk = (const float*)d_in[4];
    const float* Wv = (const float*)d_in[5];
    const float* bv = (const float*)d_in[6];
    const float* Wo = (const float*)d_in[7];
    const float* bo = (const float*)d_in[8];
    float* out = (float*)d_out;

    const int M = Mtot;                       // 4096
    char* ws = (char*)d_ws;
    unsigned short* xb  = (unsigned short*)ws;                       // 4 MB (reused as att_bf16)
    unsigned short* wqb = (unsigned short*)(ws + (4u << 20));        // 512 KB each
    unsigned short* wkb = (unsigned short*)(ws + (4u << 20) + (512u << 10));
    unsigned short* wvb = (unsigned short*)(ws + (4u << 20) + (1024u << 10));
    unsigned short* wob = (unsigned short*)(ws + (4u << 20) + (1536u << 10));
    float* qf = (float*)(ws + (6u << 20));                           // 8 MB each
    float* kf = qf + (size_t)M * D_;
    float* vf = kf + (size_t)M * D_;

    // casts
    cast_f32_bf16<<<(M * D_ / 4 + 255) / 256, 256, 0, stream>>>(x, xb, M * D_ / 4);
    cast_f32_bf16<<<(D_ * D_ / 4 + 255) / 256, 256, 0, stream>>>(Wq, wqb, D_ * D_ / 4);
    cast_f32_bf16<<<(D_ * D_ / 4 + 255) / 256, 256, 0, stream>>>(Wk, wkb, D_ * D_ / 4);
    cast_f32_bf16<<<(D_ * D_ / 4 + 255) / 256, 256, 0, stream>>>(Wv, wvb, D_ * D_ / 4);
    cast_f32_bf16<<<(D_ * D_ / 4 + 255) / 256, 256, 0, stream>>>(Wo, wob, D_ * D_ / 4);

    // Q/K/V projections (MFMA bf16)
    dim3 gg(M / GTM, D_ / GTN);               // 32 x 8
    gemm_bf16_nt<<<gg, 256, 0, stream>>>(xb, wqb, bq, qf, M, D_, D_);
    gemm_bf16_nt<<<gg, 256, 0, stream>>>(xb, wkb, bk, kf, M, D_, D_);
    gemm_bf16_nt<<<gg, 256, 0, stream>>>(xb, wvb, bv, vf, M, D_, D_);

    // local attention (writes bf16 att into xb, which is dead now)
    dim3 ga(T_ / QTB, B_ * H_);               // 32 x 16
    attn_local<<<ga, 256, 0, stream>>>(qf, kf, vf, xb);

    // output projection
    gemm_bf16_nt<<<gg, 256, 0, stream>>>(xb, wob, bo, out, M, D_, D_);
}

// Round 3
// 115.063 us; speedup vs baseline: 2.6027x; 1.3042x over previous
//
#include <hip/hip_runtime.h>

#define B_  2
#define T_  2048
#define D_  512
#define H_  8
#define HD_ 64
#define WHALF_ 16
#define Mtot (B_*T_)
#define QKV_LD 1536

typedef __attribute__((ext_vector_type(8))) short short8;   // 8 bf16 in 4 VGPRs
typedef __attribute__((ext_vector_type(4))) float floatx4;  // MFMA accumulator

__device__ __forceinline__ unsigned short f2bf(float f) {
    unsigned u = __float_as_uint(f);
    u = (u + 0x7fffu + ((u >> 16) & 1u)) >> 16;   // RNE
    return (unsigned short)u;
}

// ---------------------------------------------------------------------------
// fp32 -> bf16 cast for x
// ---------------------------------------------------------------------------
__global__ __launch_bounds__(256) void cast_f32_bf16(
    const float* __restrict__ src, unsigned short* __restrict__ dst, int n4) {
    int i = blockIdx.x * blockDim.x + threadIdx.x;
    if (i < n4) {
        float4 f = ((const float4*)src)[i];
        ushort4 o;
        o.x = f2bf(f.x); o.y = f2bf(f.y); o.z = f2bf(f.z); o.w = f2bf(f.w);
        ((ushort4*)dst)[i] = o;
    }
}

// ---------------------------------------------------------------------------
// Build fused bf16 weights: wqkv = [Wq;Wk;Wv] (1536x512), wob = Wo,
// bqkv = [bq;bk;bv] (fp32). Blocks 0..1023 cast weights; block 1024 biases.
// ---------------------------------------------------------------------------
__global__ __launch_bounds__(256) void cast_weights(
    const float* __restrict__ Wq, const float* __restrict__ Wk,
    const float* __restrict__ Wv, const float* __restrict__ Wo,
    const float* __restrict__ bq, const float* __restrict__ bk,
    const float* __restrict__ bv,
    unsigned short* __restrict__ wqkv, unsigned short* __restrict__ wob,
    float* __restrict__ bqkv)
{
    if (blockIdx.x < 1024) {
        int gid = blockIdx.x * 256 + threadIdx.x;      // 0..262143
        int m   = gid >> 16;                           // matrix 0..3
        int idx = gid & 0xFFFF;                        // float4 index in matrix
        const float* src = (m == 0) ? Wq : (m == 1) ? Wk : (m == 2) ? Wv : Wo;
        float4 f = ((const float4*)src)[idx];
        ushort4 o;
        o.x = f2bf(f.x); o.y = f2bf(f.y); o.z = f2bf(f.z); o.w = f2bf(f.w);
        if (m < 3) ((ushort4*)wqkv)[(m << 16) + idx] = o;
        else       ((ushort4*)wob)[idx] = o;
    } else {
        for (int i = threadIdx.x; i < 384; i += 256) {   // 1536 floats
            const float* src = (i < 128) ? bq : (i < 256) ? bk : bv;
            ((float4*)bqkv)[i] = ((const float4*)src)[i & 127];
        }
    }
}

// ---------------------------------------------------------------------------
// bf16 MFMA GEMM:  C[M,N] = A[M,K] @ W[N,K]^T + bias.  OUT_BF16 selects
// bf16 or fp32 output. Tile 128x64, BK=32, 4 waves, 4x2 16x16 frags/wave.
// ---------------------------------------------------------------------------
#define GTM 128
#define GTN 64
#define GBK 32
#define ALD 40

template<bool OUT_BF16>
__global__ __launch_bounds__(256) void gemm_bf16_nt(
    const unsigned short* __restrict__ A, const unsigned short* __restrict__ W,
    const float* __restrict__ bias, void* __restrict__ Cv,
    int M, int N, int K)
{
    __shared__ unsigned short As[GTM][ALD];
    __shared__ unsigned short Bs[GTN][ALD];

    const int t  = threadIdx.x;
    const int m0 = blockIdx.x * GTM;
    const int n0 = blockIdx.y * GTN;
    const int w  = t >> 6, l = t & 63;
    const int quad = l >> 4, lo = l & 15;
    const int wm = w & 1, wn = w >> 1;

    const int lrowA0 = t >> 2;
    const int lrowA1 = (t + 256) >> 2;
    const int lko    = (t & 3) * 8;

    floatx4 acc[4][2];
    #pragma unroll
    for (int i = 0; i < 4; ++i)
        #pragma unroll
        for (int j = 0; j < 2; ++j)
            acc[i][j] = (floatx4)0.0f;

    for (int k0 = 0; k0 < K; k0 += GBK) {
        *(short8*)(&As[lrowA0][lko]) =
            *(const short8*)(&A[(size_t)(m0 + lrowA0) * K + k0 + lko]);
        *(short8*)(&As[lrowA1][lko]) =
            *(const short8*)(&A[(size_t)(m0 + lrowA1) * K + k0 + lko]);
        *(short8*)(&Bs[lrowA0][lko]) =
            *(const short8*)(&W[(size_t)(n0 + lrowA0) * K + k0 + lko]);
        __syncthreads();

        short8 b0 = *(const short8*)(&Bs[wn * 32 + lo][quad * 8]);
        short8 b1 = *(const short8*)(&Bs[wn * 32 + 16 + lo][quad * 8]);
        #pragma unroll
        for (int i = 0; i < 4; ++i) {
            short8 a = *(const short8*)(&As[wm * 64 + i * 16 + lo][quad * 8]);
            acc[i][0] = __builtin_amdgcn_mfma_f32_16x16x32_bf16(a, b0, acc[i][0], 0, 0, 0);
            acc[i][1] = __builtin_amdgcn_mfma_f32_16x16x32_bf16(a, b1, acc[i][1], 0, 0, 0);
        }
        __syncthreads();
    }

    #pragma unroll
    for (int i = 0; i < 4; ++i) {
        int rbase = m0 + wm * 64 + i * 16 + quad * 4;
        #pragma unroll
        for (int jn = 0; jn < 2; ++jn) {
            int col = n0 + wn * 32 + jn * 16 + lo;
            float bv = bias[col];
            #pragma unroll
            for (int r = 0; r < 4; ++r) {
                float val = acc[i][jn][r] + bv;
                if constexpr (OUT_BF16)
                    ((unsigned short*)Cv)[(size_t)(rbase + r) * N + col] = f2bf(val);
                else
                    ((float*)Cv)[(size_t)(rbase + r) * N + col] = val;
            }
        }
    }
}

// ---------------------------------------------------------------------------
// MFMA local-window attention. Block = 4 waves = 64 queries of one (b,h).
// S = Q K^T (6 key tiles x 2 ksteps), masked softmax in C-layout,
// P -> LDS (A-layout round-trip), O = P V (V staged transposed), scale by
// 1/den in epilogue. All bf16 in/out, fp32 accumulate.
// ---------------------------------------------------------------------------
#define KR 96
#define QLD 72     // 64+8 shorts: 16B-aligned rows, 2-way banks (free)
#define VLDP 104   // 96+8 shorts

__global__ __launch_bounds__(256) void attn_mfma(
    const unsigned short* __restrict__ qkv, unsigned short* __restrict__ att)
{
    __shared__ unsigned short Qs[64][QLD];
    __shared__ unsigned short Ks[KR][QLD];
    __shared__ unsigned short Vt[64][VLDP];       // [dim][key]
    __shared__ unsigned short Pws[4][16][VLDP];   // per-wave P

    const int q0 = blockIdx.x * 64;
    const int bh = blockIdx.y;
    const int b = bh >> 3, h = bh & 7;
    const int t = threadIdx.x;
    const int wq = t >> 6, l = t & 63;
    const int quad = l >> 4, lo = l & 15;

    const size_t baseQ = (size_t)(b * T_) * QKV_LD + h * HD_;

    for (int c = t; c < 512; c += 256) {          // Q: 64 rows
        int row = c >> 3, cg = c & 7;
        *(short8*)(&Qs[row][cg * 8]) =
            *(const short8*)(&qkv[baseQ + (size_t)(q0 + row) * QKV_LD + cg * 8]);
    }
    for (int c = t; c < 768; c += 256) {          // K: 96 rows
        int row = c >> 3, cg = c & 7;
        int g = q0 - WHALF_ + row;
        short8 kv = (short8)(short)0;
        if (g >= 0 && g < T_)
            kv = *(const short8*)(&qkv[baseQ + 512 + (size_t)g * QKV_LD + cg * 8]);
        *(short8*)(&Ks[row][cg * 8]) = kv;
    }
    for (int c = t; c < 768; c += 256) {          // V transposed
        int row = c >> 3, cg = c & 7;
        int g = q0 - WHALF_ + row;
        short8 vv = (short8)(short)0;
        if (g >= 0 && g < T_)
            vv = *(const short8*)(&qkv[baseQ + 1024 + (size_t)g * QKV_LD + cg * 8]);
        #pragma unroll
        for (int j = 0; j < 8; ++j) Vt[cg * 8 + j][row] = vv[j];
    }
    __syncthreads();

    // ---- S = Q K^T ----
    floatx4 S[6];
    #pragma unroll
    for (int kt = 0; kt < 6; ++kt) S[kt] = (floatx4)0.0f;
    short8 aq[2];
    #pragma unroll
    for (int ks = 0; ks < 2; ++ks)
        aq[ks] = *(const short8*)(&Qs[wq * 16 + lo][ks * 32 + quad * 8]);
    #pragma unroll
    for (int kt = 0; kt < 6; ++kt) {
        #pragma unroll
        for (int ks = 0; ks < 2; ++ks) {
            short8 bk8 = *(const short8*)(&Ks[kt * 16 + lo][ks * 32 + quad * 8]);
            S[kt] = __builtin_amdgcn_mfma_f32_16x16x32_bf16(aq[ks], bk8, S[kt], 0, 0, 0);
        }
    }

    // ---- masked softmax; C-layout row=quad*4+r, col(key)=kt*16+lo ----
    float inv_r[4];
    #pragma unroll
    for (int r = 0; r < 4; ++r) {
        int qi = q0 + wq * 16 + quad * 4 + r;
        float mx = -1e30f;
        float sv[6]; bool vd[6];
        #pragma unroll
        for (int kt = 0; kt < 6; ++kt) {
            int j = q0 - WHALF_ + kt * 16 + lo;
            bool ok = (j >= qi - WHALF_) && (j < qi + WHALF_) && (j >= 0) && (j < T_);
            float s = S[kt][r] * 0.125f;
            sv[kt] = s; vd[kt] = ok;
            mx = (ok && s > mx) ? s : mx;
        }
        #pragma unroll
        for (int mm = 1; mm < 16; mm <<= 1) mx = fmaxf(mx, __shfl_xor(mx, mm, 16));
        float den = 0.f;
        #pragma unroll
        for (int kt = 0; kt < 6; ++kt) {
            float e = vd[kt] ? __expf(sv[kt] - mx) : 0.f;
            Pws[wq][quad * 4 + r][kt * 16 + lo] = f2bf(e);
            den += e;
        }
        #pragma unroll
        for (int mm = 1; mm < 16; mm <<= 1) den += __shfl_xor(den, mm, 16);
        inv_r[r] = 1.0f / den;
    }
    __syncthreads();

    // ---- O = P V ----
    floatx4 O[4];
    #pragma unroll
    for (int nt = 0; nt < 4; ++nt) O[nt] = (floatx4)0.0f;
    #pragma unroll
    for (int ks = 0; ks < 3; ++ks) {
        short8 ap = *(const short8*)(&Pws[wq][lo][ks * 32 + quad * 8]);
        #pragma unroll
        for (int nt = 0; nt < 4; ++nt) {
            short8 bv8 = *(const short8*)(&Vt[nt * 16 + lo][ks * 32 + quad * 8]);
            O[nt] = __builtin_amdgcn_mfma_f32_16x16x32_bf16(ap, bv8, O[nt], 0, 0, 0);
        }
    }

    // ---- epilogue: scale by 1/den, bf16 out ----
    #pragma unroll
    for (int r = 0; r < 4; ++r) {
        int qi = q0 + wq * 16 + quad * 4 + r;
        size_t rowb = (size_t)(b * T_ + qi) * D_ + h * HD_;
        #pragma unroll
        for (int nt = 0; nt < 4; ++nt)
            att[rowb + nt * 16 + lo] = f2bf(O[nt][r] * inv_r[r]);
    }
}

// ---------------------------------------------------------------------------
extern "C" void kernel_launch(void* const* d_in, const int* in_sizes, int n_in,
                              void* d_out, int out_size, void* d_ws, size_t ws_size,
                              hipStream_t stream) {
    const float* x  = (const float*)d_in[0];
    const float* Wq = (const float*)d_in[1];
    const float* bq = (const float*)d_in[2];
    const float* Wk = (const float*)d_in[3];
    const float* bk = (const float*)d_in[4];
    const float* Wv = (const float*)d_in[5];
    const float* bv = (const float*)d_in[6];
    const float* Wo = (const float*)d_in[7];
    const float* bo = (const float*)d_in[8];
    float* out = (float*)d_out;

    char* ws = (char*)d_ws;
    unsigned short* xb   = (unsigned short*)(ws);                 //  4.00 MB
    unsigned short* wqkv = (unsigned short*)(ws +  4194304);      //  1.50 MB
    unsigned short* wob  = (unsigned short*)(ws +  5767168);      //  0.50 MB
    float*          bqkv = (float*)         (ws +  6291456);      //  6 KB
    unsigned short* qkvb = (unsigned short*)(ws +  6297600);      // 12.00 MB
    unsigned short* attb = (unsigned short*)(ws + 18880512);      //  4.00 MB

    cast_f32_bf16<<<2048, 256, 0, stream>>>(x, xb, Mtot * D_ / 4);
    cast_weights<<<1025, 256, 0, stream>>>(Wq, Wk, Wv, Wo, bq, bk, bv,
                                           wqkv, wob, bqkv);

    // fused QKV projection: [4096,512] @ [1536,512]^T -> bf16 [4096,1536]
    gemm_bf16_nt<true><<<dim3(Mtot / GTM, QKV_LD / GTN), 256, 0, stream>>>(
        xb, wqkv, bqkv, qkvb, Mtot, QKV_LD, D_);

    // local attention (bf16 in/out)
    attn_mfma<<<dim3(T_ / 64, B_ * H_), 256, 0, stream>>>(qkvb, attb);

    // output projection: fp32 out
    gemm_bf16_nt<false><<<dim3(Mtot / GTM, D_ / GTN), 256, 0, stream>>>(
        attb, wob, bo, out, Mtot, D_, D_);
}

// Round 4
// 114.109 us; speedup vs baseline: 2.6244x; 1.0084x over previous
//
#include <hip/hip_runtime.h>

#define B_  2
#define T_  2048
#define D_  512
#define H_  8
#define HD_ 64
#define WHALF_ 16
#define Mtot (B_*T_)
#define QKV_LD 1536

typedef __attribute__((ext_vector_type(8))) short short8;   // 8 bf16 in 4 VGPRs
typedef __attribute__((ext_vector_type(4))) float floatx4;  // MFMA accumulator

__device__ __forceinline__ unsigned short f2bf(float f) {
    unsigned u = __float_as_uint(f);
    u = (u + 0x7fffu + ((u >> 16) & 1u)) >> 16;   // RNE
    return (unsigned short)u;
}

__device__ __forceinline__ void glds16(const unsigned short* g, unsigned short* l) {
    // async global->LDS, 16 B/lane; LDS dest = wave-uniform base + lane*16
    __builtin_amdgcn_global_load_lds(
        (const __attribute__((address_space(1))) void*)g,
        (__attribute__((address_space(3))) void*)l, 16, 0, 0);
}

// ---------------------------------------------------------------------------
// One fused cast kernel: blocks 0..2047 cast x (fp32->bf16), 2048..3071 cast
// the 4 weight matrices into wqkv=[Wq;Wk;Wv] + wob, block 3072 packs bqkv.
// ---------------------------------------------------------------------------
__global__ __launch_bounds__(256) void cast_all(
    const float* __restrict__ x,
    const float* __restrict__ Wq, const float* __restrict__ Wk,
    const float* __restrict__ Wv, const float* __restrict__ Wo,
    const float* __restrict__ bq, const float* __restrict__ bk,
    const float* __restrict__ bv,
    unsigned short* __restrict__ xb,
    unsigned short* __restrict__ wqkv, unsigned short* __restrict__ wob,
    float* __restrict__ bqkv)
{
    if (blockIdx.x < 2048) {
        int i = blockIdx.x * 256 + threadIdx.x;          // x: 2M float4 groups
        float4 f = ((const float4*)x)[i];
        ushort4 o;
        o.x = f2bf(f.x); o.y = f2bf(f.y); o.z = f2bf(f.z); o.w = f2bf(f.w);
        ((ushort4*)xb)[i] = o;
    } else if (blockIdx.x < 3072) {
        int gid = (blockIdx.x - 2048) * 256 + threadIdx.x;
        int m   = gid >> 16;                             // matrix 0..3
        int idx = gid & 0xFFFF;
        const float* src = (m == 0) ? Wq : (m == 1) ? Wk : (m == 2) ? Wv : Wo;
        float4 f = ((const float4*)src)[idx];
        ushort4 o;
        o.x = f2bf(f.x); o.y = f2bf(f.y); o.z = f2bf(f.z); o.w = f2bf(f.w);
        if (m < 3) ((ushort4*)wqkv)[(m << 16) + idx] = o;
        else       ((ushort4*)wob)[idx] = o;
    } else {
        for (int i = threadIdx.x; i < 384; i += 256) {   // 1536 bias floats
            const float* src = (i < 128) ? bq : (i < 256) ? bk : bv;
            ((float4*)bqkv)[i] = ((const float4*)src)[i & 127];
        }
    }
}

// ---------------------------------------------------------------------------
// m97-structure bf16 MFMA GEMM: C[M,N] = A[M,K] @ W[N,K]^T + bias.
// Tile 128 x TN, BK=32, global_load_lds(16B) staging into UNPADDED row-major
// LDS (64 B rows; layout is forced by the lane->lds+lane*16 mapping).
// 4 waves; wave w: wm=w&1 -> 64-row half, wn=w>>1 -> (TN/2)-col half,
// 4 x (TN/32) grid of 16x16x32 frags.
// ---------------------------------------------------------------------------
#define GBK 32

template<int TN, bool OUT_BF16>
__global__ __launch_bounds__(256) void gemm_bf16_nt(
    const unsigned short* __restrict__ A, const unsigned short* __restrict__ W,
    const float* __restrict__ bias, void* __restrict__ Cv,
    int M, int N, int K)
{
    constexpr int NJ = TN / 32;          // b-frags per wave
    __shared__ unsigned short As[128 * GBK];
    __shared__ unsigned short Bs[TN * GBK];

    const int t  = threadIdx.x;
    const int m0 = blockIdx.x * 128;
    const int n0 = blockIdx.y * TN;
    const int w  = t >> 6, l = t & 63;
    const int quad = l >> 4, lo = l & 15;
    const int wm = w & 1, wn = w >> 1;

    // staging: chunk = 16 rows x 32 cols = 1024 B; lane lr=l>>2, k-off (l&3)*8
    const int lr = l >> 2, lk = (l & 3) * 8;
    // A: 8 chunks, wave w issues 2w, 2w+1
    const unsigned short* Ag0 = A + (size_t)(m0 + (2 * w) * 16 + lr) * K + lk;
    const unsigned short* Ag1 = A + (size_t)(m0 + (2 * w + 1) * 16 + lr) * K + lk;
    unsigned short* ldsA0 = &As[(2 * w) * 512];
    unsigned short* ldsA1 = &As[(2 * w + 1) * 512];
    // B: TN/16 chunks
    const unsigned short* Bg0; const unsigned short* Bg1 = nullptr;
    unsigned short* ldsB0; unsigned short* ldsB1 = nullptr;
    if constexpr (TN == 128) {
        Bg0 = W + (size_t)(n0 + (2 * w) * 16 + lr) * K + lk;
        Bg1 = W + (size_t)(n0 + (2 * w + 1) * 16 + lr) * K + lk;
        ldsB0 = &Bs[(2 * w) * 512];
        ldsB1 = &Bs[(2 * w + 1) * 512];
    } else {                             // TN == 64: 4 chunks, one per wave
        Bg0 = W + (size_t)(n0 + w * 16 + lr) * K + lk;
        ldsB0 = &Bs[w * 512];
    }

    floatx4 acc[4][NJ];
    #pragma unroll
    for (int i = 0; i < 4; ++i)
        #pragma unroll
        for (int j = 0; j < NJ; ++j)
            acc[i][j] = (floatx4)0.0f;

    for (int k0 = 0; k0 < K; k0 += GBK) {
        glds16(Ag0 + k0, ldsA0);
        glds16(Ag1 + k0, ldsA1);
        glds16(Bg0 + k0, ldsB0);
        if constexpr (TN == 128) glds16(Bg1 + k0, ldsB1);
        __syncthreads();                 // compiler emits vmcnt(0) drain

        short8 bf[NJ];
        #pragma unroll
        for (int j = 0; j < NJ; ++j)
            bf[j] = *(const short8*)(&Bs[(wn * (TN / 2) + j * 16 + lo) * GBK + quad * 8]);
        #pragma unroll
        for (int i = 0; i < 4; ++i) {
            short8 af = *(const short8*)(&As[(wm * 64 + i * 16 + lo) * GBK + quad * 8]);
            #pragma unroll
            for (int j = 0; j < NJ; ++j)
                acc[i][j] = __builtin_amdgcn_mfma_f32_16x16x32_bf16(af, bf[j], acc[i][j], 0, 0, 0);
        }
        __syncthreads();
    }

    // epilogue: C/D layout col=lane&15, row=quad*4+reg
    #pragma unroll
    for (int i = 0; i < 4; ++i) {
        int rbase = m0 + wm * 64 + i * 16 + quad * 4;
        #pragma unroll
        for (int j = 0; j < NJ; ++j) {
            int col = n0 + wn * (TN / 2) + j * 16 + lo;
            float bv = bias[col];
            #pragma unroll
            for (int r = 0; r < 4; ++r) {
                float val = acc[i][j][r] + bv;
                if constexpr (OUT_BF16)
                    ((unsigned short*)Cv)[(size_t)(rbase + r) * N + col] = f2bf(val);
                else
                    ((float*)Cv)[(size_t)(rbase + r) * N + col] = val;
            }
        }
    }
}

// ---------------------------------------------------------------------------
// MFMA local-window attention (unchanged from round 3 — passed, ~8 us).
// ---------------------------------------------------------------------------
#define KR 96
#define QLD 72
#define VLDP 104

__global__ __launch_bounds__(256) void attn_mfma(
    const unsigned short* __restrict__ qkv, unsigned short* __restrict__ att)
{
    __shared__ unsigned short Qs[64][QLD];
    __shared__ unsigned short Ks[KR][QLD];
    __shared__ unsigned short Vt[64][VLDP];
    __shared__ unsigned short Pws[4][16][VLDP];

    const int q0 = blockIdx.x * 64;
    const int bh = blockIdx.y;
    const int b = bh >> 3, h = bh & 7;
    const int t = threadIdx.x;
    const int wq = t >> 6, l = t & 63;
    const int quad = l >> 4, lo = l & 15;

    const size_t baseQ = (size_t)(b * T_) * QKV_LD + h * HD_;

    for (int c = t; c < 512; c += 256) {
        int row = c >> 3, cg = c & 7;
        *(short8*)(&Qs[row][cg * 8]) =
            *(const short8*)(&qkv[baseQ + (size_t)(q0 + row) * QKV_LD + cg * 8]);
    }
    for (int c = t; c < 768; c += 256) {
        int row = c >> 3, cg = c & 7;
        int g = q0 - WHALF_ + row;
        short8 kv = (short8)(short)0;
        if (g >= 0 && g < T_)
            kv = *(const short8*)(&qkv[baseQ + 512 + (size_t)g * QKV_LD + cg * 8]);
        *(short8*)(&Ks[row][cg * 8]) = kv;
    }
    for (int c = t; c < 768; c += 256) {
        int row = c >> 3, cg = c & 7;
        int g = q0 - WHALF_ + row;
        short8 vv = (short8)(short)0;
        if (g >= 0 && g < T_)
            vv = *(const short8*)(&qkv[baseQ + 1024 + (size_t)g * QKV_LD + cg * 8]);
        #pragma unroll
        for (int j = 0; j < 8; ++j) Vt[cg * 8 + j][row] = vv[j];
    }
    __syncthreads();

    floatx4 S[6];
    #pragma unroll
    for (int kt = 0; kt < 6; ++kt) S[kt] = (floatx4)0.0f;
    short8 aq[2];
    #pragma unroll
    for (int ks = 0; ks < 2; ++ks)
        aq[ks] = *(const short8*)(&Qs[wq * 16 + lo][ks * 32 + quad * 8]);
    #pragma unroll
    for (int kt = 0; kt < 6; ++kt) {
        #pragma unroll
        for (int ks = 0; ks < 2; ++ks) {
            short8 bk8 = *(const short8*)(&Ks[kt * 16 + lo][ks * 32 + quad * 8]);
            S[kt] = __builtin_amdgcn_mfma_f32_16x16x32_bf16(aq[ks], bk8, S[kt], 0, 0, 0);
        }
    }

    float inv_r[4];
    #pragma unroll
    for (int r = 0; r < 4; ++r) {
        int qi = q0 + wq * 16 + quad * 4 + r;
        float mx = -1e30f;
        float sv[6]; bool vd[6];
        #pragma unroll
        for (int kt = 0; kt < 6; ++kt) {
            int j = q0 - WHALF_ + kt * 16 + lo;
            bool ok = (j >= qi - WHALF_) && (j < qi + WHALF_) && (j >= 0) && (j < T_);
            float s = S[kt][r] * 0.125f;
            sv[kt] = s; vd[kt] = ok;
            mx = (ok && s > mx) ? s : mx;
        }
        #pragma unroll
        for (int mm = 1; mm < 16; mm <<= 1) mx = fmaxf(mx, __shfl_xor(mx, mm, 16));
        float den = 0.f;
        #pragma unroll
        for (int kt = 0; kt < 6; ++kt) {
            float e = vd[kt] ? __expf(sv[kt] - mx) : 0.f;
            Pws[wq][quad * 4 + r][kt * 16 + lo] = f2bf(e);
            den += e;
        }
        #pragma unroll
        for (int mm = 1; mm < 16; mm <<= 1) den += __shfl_xor(den, mm, 16);
        inv_r[r] = 1.0f / den;
    }
    __syncthreads();

    floatx4 O[4];
    #pragma unroll
    for (int nt = 0; nt < 4; ++nt) O[nt] = (floatx4)0.0f;
    #pragma unroll
    for (int ks = 0; ks < 3; ++ks) {
        short8 ap = *(const short8*)(&Pws[wq][lo][ks * 32 + quad * 8]);
        #pragma unroll
        for (int nt = 0; nt < 4; ++nt) {
            short8 bv8 = *(const short8*)(&Vt[nt * 16 + lo][ks * 32 + quad * 8]);
            O[nt] = __builtin_amdgcn_mfma_f32_16x16x32_bf16(ap, bv8, O[nt], 0, 0, 0);
        }
    }

    #pragma unroll
    for (int r = 0; r < 4; ++r) {
        int qi = q0 + wq * 16 + quad * 4 + r;
        size_t rowb = (size_t)(b * T_ + qi) * D_ + h * HD_;
        #pragma unroll
        for (int nt = 0; nt < 4; ++nt)
            att[rowb + nt * 16 + lo] = f2bf(O[nt][r] * inv_r[r]);
    }
}

// ---------------------------------------------------------------------------
extern "C" void kernel_launch(void* const* d_in, const int* in_sizes, int n_in,
                              void* d_out, int out_size, void* d_ws, size_t ws_size,
                              hipStream_t stream) {
    const float* x  = (const float*)d_in[0];
    const float* Wq = (const float*)d_in[1];
    const float* bq = (const float*)d_in[2];
    const float* Wk = (const float*)d_in[3];
    const float* bk = (const float*)d_in[4];
    const float* Wv = (const float*)d_in[5];
    const float* bv = (const float*)d_in[6];
    const float* Wo = (const float*)d_in[7];
    const float* bo = (const float*)d_in[8];
    float* out = (float*)d_out;

    char* ws = (char*)d_ws;
    unsigned short* xb   = (unsigned short*)(ws);                 //  4.00 MB
    unsigned short* wqkv = (unsigned short*)(ws +  4194304);      //  1.50 MB
    unsigned short* wob  = (unsigned short*)(ws +  5767168);      //  0.50 MB
    float*          bqkv = (float*)         (ws +  6291456);      //  6 KB
    unsigned short* qkvb = (unsigned short*)(ws +  6297600);      // 12.00 MB
    unsigned short* attb = (unsigned short*)(ws + 18880512);      //  4.00 MB

    cast_all<<<3073, 256, 0, stream>>>(x, Wq, Wk, Wv, Wo, bq, bk, bv,
                                       xb, wqkv, wob, bqkv);

    // fused QKV projection: [4096,512] @ [1536,512]^T -> bf16 [4096,1536]
    gemm_bf16_nt<128, true><<<dim3(Mtot / 128, QKV_LD / 128), 256, 0, stream>>>(
        xb, wqkv, bqkv, qkvb, Mtot, QKV_LD, D_);

    // local attention (bf16 in/out)
    attn_mfma<<<dim3(T_ / 64, B_ * H_), 256, 0, stream>>>(qkvb, attb);

    // output projection: fp32 out
    gemm_bf16_nt<64, false><<<dim3(Mtot / 128, D_ / 64), 256, 0, stream>>>(
        attb, wob, bo, out, Mtot, D_, D_);
}